// Round 2
// baseline (86.765 us; speedup 1.0000x reference)
//
#include <hip/hip_runtime.h>

#define EPS_F 1e-5f
#define BGRAPHS 4096
#define SENTINEL 0x7F7F7F7F   // memset pattern 0x7F, > N, acts as +inf

typedef float f32x4 __attribute__((ext_vector_type(4)));

// Detect whether the batch buffer is little-endian int64 viewed as int32.
// n is even; if int64, slot n-1 is a high word == 0; if int32, it's 4095 (sorted max).
__device__ __forceinline__ int batch_shift(const int* __restrict__ batch, int n) {
    return (batch[n - 1] == 0) ? 1 : 0;   // 1 -> stride-2 int32 reads (int64 data)
}

__global__ __launch_bounds__(256) void se3_seg_reduce(
    const float* __restrict__ pos, const int* __restrict__ batch,
    float* __restrict__ sums, float* __restrict__ cnts,
    int* __restrict__ starts, int n)
{
    const int tid  = blockIdx.x * blockDim.x + threadIdx.x;
    const int base = tid * 4;
    const int lane = threadIdx.x & 63;
    const int shift = batch_shift(batch, n);

    int   cur_b = -1;
    float cur_s = 0.f, cur_c = 0.f;

    if (base < n) {
        int   b4[4];
        float nrm[4];
        int   prev;
        const int nb = min(4, n - base);
        if (nb == 4) {
            if (shift == 0) {
                const int4 bi = *reinterpret_cast<const int4*>(batch + base);
                b4[0] = bi.x; b4[1] = bi.y; b4[2] = bi.z; b4[3] = bi.w;
            } else {
                const int4 v0 = *reinterpret_cast<const int4*>(batch + 2 * base);
                const int4 v1 = *reinterpret_cast<const int4*>(batch + 2 * base + 4);
                b4[0] = v0.x; b4[1] = v0.z; b4[2] = v1.x; b4[3] = v1.z;
            }
            // previous node's batch id: lane l-1's last element; wave lane 0 loads it
            const int up = __shfl_up(b4[3], 1);
            if (lane == 0) prev = (base == 0) ? -1 : batch[(size_t)(base - 1) << shift];
            else           prev = up;

            const float4* p = reinterpret_cast<const float4*>(pos + (size_t)base * 3);
            const float4 a = p[0], b = p[1], c = p[2];
            nrm[0] = sqrtf(a.x * a.x + a.y * a.y + a.z * a.z);
            nrm[1] = sqrtf(a.w * a.w + b.x * b.x + b.y * b.y);
            nrm[2] = sqrtf(b.z * b.z + b.w * b.w + c.x * c.x);
            nrm[3] = sqrtf(c.y * c.y + c.z * c.z + c.w * c.w);
        } else {
            for (int j = 0; j < 4; ++j) { b4[j] = -1; nrm[j] = 0.f; }
            for (int j = 0; j < nb; ++j) {
                b4[j] = batch[(size_t)(base + j) << shift];
                const float x = pos[(size_t)(base + j) * 3 + 0];
                const float y = pos[(size_t)(base + j) * 3 + 1];
                const float z = pos[(size_t)(base + j) * 3 + 2];
                nrm[j] = sqrtf(x * x + y * y + z * z);
            }
            prev = (base == 0) ? -1 : batch[(size_t)(base - 1) << shift];
        }

        // segment-start detection (unique writer per segment -> plain store)
        if (b4[0] >= 0 && b4[0] != prev) starts[b4[0]] = base;
        #pragma unroll
        for (int j = 1; j < 4; ++j)
            if (b4[j] >= 0 && b4[j] != b4[j - 1]) starts[b4[j]] = base + j;

        // per-thread run accumulation (batch is sorted; boundaries are rare)
        cur_b = b4[0];
        cur_s = nrm[0];
        cur_c = (b4[0] >= 0) ? 1.f : 0.f;
        #pragma unroll
        for (int j = 1; j < 4; ++j) {
            if (b4[j] == cur_b) { cur_s += nrm[j]; cur_c += 1.f; }
            else {
                if (cur_b >= 0) { atomicAdd(&sums[cur_b], cur_s); atomicAdd(&cnts[cur_b], cur_c); }
                cur_b = b4[j]; cur_s = nrm[j]; cur_c = (b4[j] >= 0) ? 1.f : 0.f;
            }
        }
    }

    // wave-level segmented reduction over each lane's last run (keys non-decreasing)
    #pragma unroll
    for (int off = 1; off < 64; off <<= 1) {
        const float os = __shfl_down(cur_s, off);
        const float oc = __shfl_down(cur_c, off);
        const int   ob = __shfl_down(cur_b, off);
        if (lane + off < 64 && ob == cur_b) { cur_s += os; cur_c += oc; }
    }
    const int pb = __shfl_up(cur_b, 1);
    if ((lane == 0 || pb != cur_b) && cur_b >= 0) {
        atomicAdd(&sums[cur_b], cur_s);
        atomicAdd(&cnts[cur_b], cur_c);
    }
}

// One block: suffix-min scan over starts (monotone lookup table even with empty
// graphs) + per-graph scale = w / (sum/max(cnt,1) + eps).
__global__ __launch_bounds__(1024) void se3_finalize(
    const float* __restrict__ sums, const float* __restrict__ cnts,
    const float* __restrict__ w, float* __restrict__ scale, int* __restrict__ starts)
{
    __shared__ int ta[BGRAPHS], tb[BGRAPHS];
    const int t = threadIdx.x;
    for (int i = t; i < BGRAPHS; i += 1024) ta[i] = starts[i];
    __syncthreads();
    int* src = ta; int* dst = tb;
    for (int stride = 1; stride < BGRAPHS; stride <<= 1) {
        for (int i = t; i < BGRAPHS; i += 1024) {
            int v = src[i];
            if (i + stride < BGRAPHS) v = min(v, src[i + stride]);
            dst[i] = v;
        }
        __syncthreads();
        int* tmp = src; src = dst; dst = tmp;
    }
    for (int i = t; i < BGRAPHS; i += 1024) {
        starts[i] = src[i];
        const float mean = sums[i] / fmaxf(cnts[i], 1.f);
        scale[i] = w[0] / (mean + EPS_F);
    }
}

// max b such that t[b] <= i  (t non-decreasing, t[0] == 0)
__device__ __forceinline__ int find_seg(const int* __restrict__ t, int i) {
    int lo = 0, hi = BGRAPHS - 1;
    #pragma unroll
    for (int s = 0; s < 12; ++s) {
        const int mid = (lo + hi + 1) >> 1;
        if (t[mid] <= i) lo = mid; else hi = mid - 1;
    }
    return lo;
}

__global__ __launch_bounds__(256) void se3_apply(
    const float* __restrict__ pos, const int* __restrict__ tstarts,
    const float* __restrict__ scale, float* __restrict__ out, int n)
{
    __shared__ int   s_t[BGRAPHS];
    __shared__ float s_s[BGRAPHS];
    for (int i = threadIdx.x; i < BGRAPHS / 4; i += blockDim.x) {
        reinterpret_cast<int4*>(s_t)[i]   = reinterpret_cast<const int4*>(tstarts)[i];
        reinterpret_cast<float4*>(s_s)[i] = reinterpret_cast<const float4*>(scale)[i];
    }
    __syncthreads();

    const int tid  = blockIdx.x * blockDim.x + threadIdx.x;
    const int base = tid * 4;
    if (base >= n) return;

    int g = find_seg(s_t, base);
    float sc[4];
    sc[0] = s_s[g];
    #pragma unroll
    for (int j = 1; j < 4; ++j) {
        while (g < BGRAPHS - 1 && s_t[g + 1] <= base + j) ++g;
        sc[j] = s_s[g];
    }

    if (base + 4 <= n) {
        const float4* p = reinterpret_cast<const float4*>(pos + (size_t)base * 3);
        const float4 a = p[0], b = p[1], c = p[2];
        f32x4* q = reinterpret_cast<f32x4*>(out + (size_t)base * 3);
        f32x4 o0 = { a.x * sc[0], a.y * sc[0], a.z * sc[0], a.w * sc[1] };
        f32x4 o1 = { b.x * sc[1], b.y * sc[1], b.z * sc[2], b.w * sc[2] };
        f32x4 o2 = { c.x * sc[2], c.y * sc[3], c.z * sc[3], c.w * sc[3] };
        __builtin_nontemporal_store(o0, q + 0);
        __builtin_nontemporal_store(o1, q + 1);
        __builtin_nontemporal_store(o2, q + 2);
    } else {
        for (int j = 0; j < n - base; ++j) {
            out[(size_t)(base + j) * 3 + 0] = pos[(size_t)(base + j) * 3 + 0] * sc[j];
            out[(size_t)(base + j) * 3 + 1] = pos[(size_t)(base + j) * 3 + 1] * sc[j];
            out[(size_t)(base + j) * 3 + 2] = pos[(size_t)(base + j) * 3 + 2] * sc[j];
        }
    }
}

extern "C" void kernel_launch(void* const* d_in, const int* in_sizes, int n_in,
                              void* d_out, int out_size, void* d_ws, size_t ws_size,
                              hipStream_t stream)
{
    const float* pos   = (const float*)d_in[0];
    const int*   batch = (const int*)d_in[1];
    const float* w     = (const float*)d_in[2];
    float*       out   = (float*)d_out;
    const int    n     = in_sizes[1];

    float* sums   = (float*)d_ws;
    float* cnts   = sums + BGRAPHS;
    float* scale  = cnts + BGRAPHS;
    int*   starts = (int*)(scale + BGRAPHS);

    // re-init accumulators every call (ws is poisoned once, never restored)
    hipMemsetAsync(d_ws, 0, 2 * BGRAPHS * sizeof(float), stream);          // sums, cnts = 0
    hipMemsetAsync(starts, 0x7F, BGRAPHS * sizeof(int), stream);           // starts = +inf

    const int nthreads = (n + 3) / 4;
    const int blocks   = (nthreads + 255) / 256;
    se3_seg_reduce<<<blocks, 256, 0, stream>>>(pos, batch, sums, cnts, starts, n);
    se3_finalize<<<1, 1024, 0, stream>>>(sums, cnts, w, scale, starts);
    se3_apply<<<blocks, 256, 0, stream>>>(pos, starts, scale, out, n);
}

// Round 3
// 78.498 us; speedup vs baseline: 1.1053x; 1.1053x over previous
//
#include <hip/hip_runtime.h>

#define EPS_F 1e-5f
#define BGRAPHS 4096
#define NODES_PER_BLOCK 1024   // 256 threads * 4 nodes

// Detect whether the batch buffer is little-endian int64 viewed as int32.
// n is even; if int64, slot n-1 is a high word == 0; if int32, it's 4095 (sorted max).
__device__ __forceinline__ int batch_shift(const int* __restrict__ batch, int n) {
    return (batch[n - 1] == 0) ? 1 : 0;   // 1 -> stride-2 int32 reads (int64 data)
}

__global__ __launch_bounds__(256) void se3_seg_reduce(
    const float* __restrict__ pos, const int* __restrict__ batch,
    float* __restrict__ sums, float* __restrict__ cnts,
    int* __restrict__ starts, int n)
{
    const int tid  = blockIdx.x * blockDim.x + threadIdx.x;
    const int base = tid * 4;
    const int lane = threadIdx.x & 63;
    const int shift = batch_shift(batch, n);

    int   cur_b = -1;
    float cur_s = 0.f, cur_c = 0.f;

    if (base < n) {
        int   b4[4];
        float nrm[4];
        int   prev;
        const int nb = min(4, n - base);
        if (nb == 4) {
            if (shift == 0) {
                const int4 bi = *reinterpret_cast<const int4*>(batch + base);
                b4[0] = bi.x; b4[1] = bi.y; b4[2] = bi.z; b4[3] = bi.w;
            } else {
                const int4 v0 = *reinterpret_cast<const int4*>(batch + 2 * base);
                const int4 v1 = *reinterpret_cast<const int4*>(batch + 2 * base + 4);
                b4[0] = v0.x; b4[1] = v0.z; b4[2] = v1.x; b4[3] = v1.z;
            }
            // previous node's batch id: lane l-1's last element; wave lane 0 loads it
            const int up = __shfl_up(b4[3], 1);
            if (lane == 0) prev = (base == 0) ? -1 : batch[(size_t)(base - 1) << shift];
            else           prev = up;

            const float4* p = reinterpret_cast<const float4*>(pos + (size_t)base * 3);
            const float4 a = p[0], b = p[1], c = p[2];
            nrm[0] = sqrtf(a.x * a.x + a.y * a.y + a.z * a.z);
            nrm[1] = sqrtf(a.w * a.w + b.x * b.x + b.y * b.y);
            nrm[2] = sqrtf(b.z * b.z + b.w * b.w + c.x * c.x);
            nrm[3] = sqrtf(c.y * c.y + c.z * c.z + c.w * c.w);
        } else {
            for (int j = 0; j < 4; ++j) { b4[j] = -1; nrm[j] = 0.f; }
            for (int j = 0; j < nb; ++j) {
                b4[j] = batch[(size_t)(base + j) << shift];
                const float x = pos[(size_t)(base + j) * 3 + 0];
                const float y = pos[(size_t)(base + j) * 3 + 1];
                const float z = pos[(size_t)(base + j) * 3 + 2];
                nrm[j] = sqrtf(x * x + y * y + z * z);
            }
            prev = (base == 0) ? -1 : batch[(size_t)(base - 1) << shift];
        }

        // segment-start detection (unique writer per segment -> plain store)
        if (b4[0] >= 0 && b4[0] != prev) starts[b4[0]] = base;
        #pragma unroll
        for (int j = 1; j < 4; ++j)
            if (b4[j] >= 0 && b4[j] != b4[j - 1]) starts[b4[j]] = base + j;

        // per-thread run accumulation (batch is sorted; boundaries are rare)
        cur_b = b4[0];
        cur_s = nrm[0];
        cur_c = (b4[0] >= 0) ? 1.f : 0.f;
        #pragma unroll
        for (int j = 1; j < 4; ++j) {
            if (b4[j] == cur_b) { cur_s += nrm[j]; cur_c += 1.f; }
            else {
                if (cur_b >= 0) { atomicAdd(&sums[cur_b], cur_s); atomicAdd(&cnts[cur_b], cur_c); }
                cur_b = b4[j]; cur_s = nrm[j]; cur_c = (b4[j] >= 0) ? 1.f : 0.f;
            }
        }
    }

    // wave-level segmented reduction over each lane's last run (keys non-decreasing)
    #pragma unroll
    for (int off = 1; off < 64; off <<= 1) {
        const float os = __shfl_down(cur_s, off);
        const float oc = __shfl_down(cur_c, off);
        const int   ob = __shfl_down(cur_b, off);
        if (lane + off < 64 && ob == cur_b) { cur_s += os; cur_c += oc; }
    }
    const int pb = __shfl_up(cur_b, 1);
    if ((lane == 0 || pb != cur_b) && cur_b >= 0) {
        atomicAdd(&sums[cur_b], cur_s);
        atomicAdd(&cnts[cur_b], cur_c);
    }
}

// One block: suffix-min scan over starts (monotone lookup even with empty graphs),
// per-graph scale = w / (sum/max(cnt,1) + eps), and per-apply-block coarse index
// cg[blk] = max g such that t[g] <= blk*NODES_PER_BLOCK.
__global__ __launch_bounds__(1024) void se3_finalize(
    const float* __restrict__ sums, const float* __restrict__ cnts,
    const float* __restrict__ w, float* __restrict__ scale,
    int* __restrict__ starts, int* __restrict__ cg, int nchunks)
{
    __shared__ int ta[BGRAPHS], tb[BGRAPHS];
    const int t = threadIdx.x;
    for (int i = t; i < BGRAPHS; i += 1024) ta[i] = starts[i];
    __syncthreads();
    int* src = ta; int* dst = tb;
    for (int stride = 1; stride < BGRAPHS; stride <<= 1) {
        for (int i = t; i < BGRAPHS; i += 1024) {
            int v = src[i];
            if (i + stride < BGRAPHS) v = min(v, src[i + stride]);
            dst[i] = v;
        }
        __syncthreads();
        int* tmp = src; src = dst; dst = tmp;
    }
    for (int i = t; i < BGRAPHS; i += 1024) {
        starts[i] = src[i];
        const float mean = sums[i] / fmaxf(cnts[i], 1.f);
        scale[i] = w[0] / (mean + EPS_F);
    }
    // coarse per-chunk start graph: binary search in LDS
    for (int c = t; c < nchunks; c += 1024) {
        const int x = c * NODES_PER_BLOCK;
        int lo = 0, hi = BGRAPHS - 1;
        #pragma unroll
        for (int s = 0; s < 12; ++s) {
            const int mid = (lo + hi + 1) >> 1;
            if (src[mid] <= x) lo = mid; else hi = mid - 1;
        }
        cg[c] = lo;
    }
}

__global__ __launch_bounds__(256) void se3_apply(
    const float* __restrict__ pos, const int* __restrict__ t,
    const float* __restrict__ scale, const int* __restrict__ cg,
    float* __restrict__ out, int n)
{
    const int tid  = blockIdx.x * blockDim.x + threadIdx.x;
    const int base = tid * 4;
    if (base >= n) return;

    // coarse index for this block, then forward walk (t, scale are 16 KB each:
    // L1/L2-resident broadcast loads; <=~1 boundary per 1024-node block typical)
    int g = cg[blockIdx.x];
    while (g < BGRAPHS - 1 && t[g + 1] <= base) ++g;
    float sc[4];
    sc[0] = scale[g];
    #pragma unroll
    for (int j = 1; j < 4; ++j) {
        while (g < BGRAPHS - 1 && t[g + 1] <= base + j) ++g;
        sc[j] = scale[g];
    }

    if (base + 4 <= n) {
        const float4* p = reinterpret_cast<const float4*>(pos + (size_t)base * 3);
        const float4 a = p[0], b = p[1], c = p[2];
        float4* q = reinterpret_cast<float4*>(out + (size_t)base * 3);
        q[0] = make_float4(a.x * sc[0], a.y * sc[0], a.z * sc[0], a.w * sc[1]);
        q[1] = make_float4(b.x * sc[1], b.y * sc[1], b.z * sc[2], b.w * sc[2]);
        q[2] = make_float4(c.x * sc[2], c.y * sc[3], c.z * sc[3], c.w * sc[3]);
    } else {
        for (int j = 0; j < n - base; ++j) {
            out[(size_t)(base + j) * 3 + 0] = pos[(size_t)(base + j) * 3 + 0] * sc[j];
            out[(size_t)(base + j) * 3 + 1] = pos[(size_t)(base + j) * 3 + 1] * sc[j];
            out[(size_t)(base + j) * 3 + 2] = pos[(size_t)(base + j) * 3 + 2] * sc[j];
        }
    }
}

extern "C" void kernel_launch(void* const* d_in, const int* in_sizes, int n_in,
                              void* d_out, int out_size, void* d_ws, size_t ws_size,
                              hipStream_t stream)
{
    const float* pos   = (const float*)d_in[0];
    const int*   batch = (const int*)d_in[1];
    const float* w     = (const float*)d_in[2];
    float*       out   = (float*)d_out;
    const int    n     = in_sizes[1];

    float* sums   = (float*)d_ws;
    float* cnts   = sums + BGRAPHS;
    float* scale  = cnts + BGRAPHS;
    int*   starts = (int*)(scale + BGRAPHS);
    int*   cg     = starts + BGRAPHS;

    const int nthreads = (n + 3) / 4;
    const int blocks   = (nthreads + 255) / 256;

    // re-init accumulators every call (ws is poisoned once, never restored)
    hipMemsetAsync(d_ws, 0, 2 * BGRAPHS * sizeof(float), stream);   // sums, cnts = 0
    hipMemsetAsync(starts, 0x7F, BGRAPHS * sizeof(int), stream);    // starts = +inf

    se3_seg_reduce<<<blocks, 256, 0, stream>>>(pos, batch, sums, cnts, starts, n);
    se3_finalize<<<1, 1024, 0, stream>>>(sums, cnts, w, scale, starts, cg, blocks);
    se3_apply<<<blocks, 256, 0, stream>>>(pos, starts, scale, cg, out, n);
}

// Round 4
// 74.373 us; speedup vs baseline: 1.1666x; 1.0555x over previous
//
#include <hip/hip_runtime.h>

#define EPS_F 1e-5f
#define BGRAPHS 4096

typedef float f32x4 __attribute__((ext_vector_type(4)));

// Detect whether the batch buffer is little-endian int64 viewed as int32.
// n is even; if int64, slot n-1 is a high word == 0; if int32, it's 4095 (sorted max).
__device__ __forceinline__ int batch_shift(const int* __restrict__ batch, int n) {
    return (batch[n - 1] == 0) ? 1 : 0;   // 1 -> stride-2 int32 reads (int64 data)
}

__global__ __launch_bounds__(256) void se3_seg_reduce(
    const float* __restrict__ pos, const int* __restrict__ batch,
    float* __restrict__ sums, float* __restrict__ cnts, int n)
{
    const int tid  = blockIdx.x * blockDim.x + threadIdx.x;
    const int base = tid * 4;
    const int lane = threadIdx.x & 63;
    const int shift = batch_shift(batch, n);

    int   cur_b = -1;
    float cur_s = 0.f, cur_c = 0.f;

    if (base < n) {
        int   b4[4];
        float nrm[4];
        const int nb = min(4, n - base);
        if (nb == 4) {
            if (shift == 0) {
                const int4 bi = *reinterpret_cast<const int4*>(batch + base);
                b4[0] = bi.x; b4[1] = bi.y; b4[2] = bi.z; b4[3] = bi.w;
            } else {
                const int4 v0 = *reinterpret_cast<const int4*>(batch + 2 * base);
                const int4 v1 = *reinterpret_cast<const int4*>(batch + 2 * base + 4);
                b4[0] = v0.x; b4[1] = v0.z; b4[2] = v1.x; b4[3] = v1.z;
            }
            const float4* p = reinterpret_cast<const float4*>(pos + (size_t)base * 3);
            const float4 a = p[0], b = p[1], c = p[2];
            nrm[0] = sqrtf(a.x * a.x + a.y * a.y + a.z * a.z);
            nrm[1] = sqrtf(a.w * a.w + b.x * b.x + b.y * b.y);
            nrm[2] = sqrtf(b.z * b.z + b.w * b.w + c.x * c.x);
            nrm[3] = sqrtf(c.y * c.y + c.z * c.z + c.w * c.w);
        } else {
            for (int j = 0; j < 4; ++j) { b4[j] = -1; nrm[j] = 0.f; }
            for (int j = 0; j < nb; ++j) {
                b4[j] = batch[(size_t)(base + j) << shift];
                const float x = pos[(size_t)(base + j) * 3 + 0];
                const float y = pos[(size_t)(base + j) * 3 + 1];
                const float z = pos[(size_t)(base + j) * 3 + 2];
                nrm[j] = sqrtf(x * x + y * y + z * z);
            }
        }
        // per-thread run accumulation (batch is sorted; boundaries are rare)
        cur_b = b4[0];
        cur_s = nrm[0];
        cur_c = (b4[0] >= 0) ? 1.f : 0.f;
        #pragma unroll
        for (int j = 1; j < 4; ++j) {
            if (b4[j] == cur_b) { cur_s += nrm[j]; cur_c += 1.f; }
            else {
                if (cur_b >= 0) { atomicAdd(&sums[cur_b], cur_s); atomicAdd(&cnts[cur_b], cur_c); }
                cur_b = b4[j]; cur_s = nrm[j]; cur_c = (b4[j] >= 0) ? 1.f : 0.f;
            }
        }
    }

    // wave-level segmented reduction over each lane's last run (keys non-decreasing)
    #pragma unroll
    for (int off = 1; off < 64; off <<= 1) {
        const float os = __shfl_down(cur_s, off);
        const float oc = __shfl_down(cur_c, off);
        const int   ob = __shfl_down(cur_b, off);
        if (lane + off < 64 && ob == cur_b) { cur_s += os; cur_c += oc; }
    }
    const int pb = __shfl_up(cur_b, 1);
    if ((lane == 0 || pb != cur_b) && cur_b >= 0) {
        atomicAdd(&sums[cur_b], cur_s);
        atomicAdd(&cnts[cur_b], cur_c);
    }
}

__global__ void se3_finalize(const float* __restrict__ sums, const float* __restrict__ cnts,
                             const float* __restrict__ w, float* __restrict__ scale)
{
    const int b = blockIdx.x * blockDim.x + threadIdx.x;
    if (b < BGRAPHS) {
        const float mean = sums[b] / fmaxf(cnts[b], 1.f);
        scale[b] = w[0] / (mean + EPS_F);
    }
}

__global__ __launch_bounds__(256) void se3_apply(
    const float* __restrict__ pos, const int* __restrict__ batch,
    const float* __restrict__ scale, float* __restrict__ out, int n)
{
    const int tid  = blockIdx.x * blockDim.x + threadIdx.x;
    const int base = tid * 4;
    if (base >= n) return;
    const int shift = batch_shift(batch, n);
    if (base + 4 <= n) {
        int b4[4];
        if (shift == 0) {
            const int4 bi = *reinterpret_cast<const int4*>(batch + base);
            b4[0] = bi.x; b4[1] = bi.y; b4[2] = bi.z; b4[3] = bi.w;
        } else {
            const int4 v0 = *reinterpret_cast<const int4*>(batch + 2 * base);
            const int4 v1 = *reinterpret_cast<const int4*>(batch + 2 * base + 4);
            b4[0] = v0.x; b4[1] = v0.z; b4[2] = v1.x; b4[3] = v1.z;
        }
        const float s0 = scale[b4[0]], s1 = scale[b4[1]], s2 = scale[b4[2]], s3 = scale[b4[3]];
        const float4* p = reinterpret_cast<const float4*>(pos + (size_t)base * 3);
        const float4 a = p[0], b = p[1], c = p[2];
        // non-temporal: keep the streamed output from evicting pos/batch out of L3
        f32x4* q = reinterpret_cast<f32x4*>(out + (size_t)base * 3);
        f32x4 o0 = { a.x * s0, a.y * s0, a.z * s0, a.w * s1 };
        f32x4 o1 = { b.x * s1, b.y * s1, b.z * s2, b.w * s2 };
        f32x4 o2 = { c.x * s2, c.y * s3, c.z * s3, c.w * s3 };
        __builtin_nontemporal_store(o0, q + 0);
        __builtin_nontemporal_store(o1, q + 1);
        __builtin_nontemporal_store(o2, q + 2);
    } else {
        for (int j = 0; j < n - base; ++j) {
            const int bb = batch[(size_t)(base + j) << shift];
            const float s = scale[bb];
            out[(size_t)(base + j) * 3 + 0] = pos[(size_t)(base + j) * 3 + 0] * s;
            out[(size_t)(base + j) * 3 + 1] = pos[(size_t)(base + j) * 3 + 1] * s;
            out[(size_t)(base + j) * 3 + 2] = pos[(size_t)(base + j) * 3 + 2] * s;
        }
    }
}

extern "C" void kernel_launch(void* const* d_in, const int* in_sizes, int n_in,
                              void* d_out, int out_size, void* d_ws, size_t ws_size,
                              hipStream_t stream)
{
    const float* pos   = (const float*)d_in[0];
    const int*   batch = (const int*)d_in[1];
    const float* w     = (const float*)d_in[2];
    float*       out   = (float*)d_out;
    const int    n     = in_sizes[1];

    float* sums  = (float*)d_ws;
    float* cnts  = sums + BGRAPHS;
    float* scale = cnts + BGRAPHS;

    // zero the accumulators every call (harness poisons ws once, never restores)
    hipMemsetAsync(d_ws, 0, 2 * BGRAPHS * sizeof(float), stream);

    const int nthreads = (n + 3) / 4;
    const int blocks   = (nthreads + 255) / 256;
    se3_seg_reduce<<<blocks, 256, 0, stream>>>(pos, batch, sums, cnts, n);
    se3_finalize<<<(BGRAPHS + 255) / 256, 256, 0, stream>>>(sums, cnts, w, scale);
    se3_apply<<<blocks, 256, 0, stream>>>(pos, batch, scale, out, n);
}